// Round 3
// baseline (137.766 us; speedup 1.0000x reference)
//
#include <hip/hip_runtime.h>
#include <stdint.h>

#define KN 9
#define HH 64
#define WW 64
#define CC 128
#define FF 128
#define TM 32    // pixels per block
#define LDK 136  // padded LDS K-stride (bf16 elements)

typedef __bf16 bf16x8 __attribute__((ext_vector_type(8)));
typedef float f32x4 __attribute__((ext_vector_type(4)));
typedef unsigned short us8 __attribute__((ext_vector_type(8)));
typedef unsigned short us4 __attribute__((ext_vector_type(4)));

// Reference tap layout: stack(meshgrid(ij)) has shape (2,3,3); reshape(-1,2)
// flattens C-order (I-grid row-major, then J-grid row-major) and pairs
// CONSECUTIVE elements across the boundary:
//   seq = [0,0,0,1,1,1,2,2,2, 0,1,2,0,1,2,0,1,2]
//   taps: (0,0)(0,1)(1,1)(2,2)(2,0)(1,2)(0,1)(2,0)(1,2)
// NOT a permutation of the 3x3 grid — faithful to the TF quirk.
__constant__ float c_init_i[KN] = {0.f,0.f,1.f,2.f,2.f,1.f,0.f,2.f,1.f};
__constant__ float c_init_j[KN] = {0.f,1.f,1.f,2.f,0.f,2.f,1.f,0.f,2.f};

static __device__ inline unsigned short f2bf(float f) {
    union { float f; unsigned u; } v; v.f = f;
    unsigned r = v.u + 0x7fffu + ((v.u >> 16) & 1u);  // RNE
    return (unsigned short)(r >> 16);
}

// Transpose + quantize W: (KN, C, F) fp32 -> Wt (KN, F, C) bf16
__global__ void wt_kernel(const float* __restrict__ Wk, unsigned short* __restrict__ Wt) {
    int idx = blockIdx.x * 256 + threadIdx.x;
    if (idx >= KN * CC * FF) return;
    int n = idx >> 14;            // /(128*128)
    int rem = idx & 16383;
    int f = rem >> 7;
    int c = rem & 127;
    Wt[idx] = f2bf(Wk[(n << 14) + (c << 7) + f]);
}

__launch_bounds__(256)
__global__ void deform_kernel(const float* __restrict__ xin,
                              const float* __restrict__ off,
                              const unsigned short* __restrict__ Wt,
                              const float* __restrict__ bias,
                              float* __restrict__ out) {
    __shared__ unsigned short As[TM][LDK];   // deform tile, bf16, M x Kchunk
    __shared__ unsigned short Bt[FF][LDK];   // W tap, bf16, N x Kchunk (B^T layout)
    __shared__ float cY[TM][KN];
    __shared__ float cX[TM][KN];

    const int tid  = threadIdx.x;
    const int pix0 = blockIdx.x * TM;        // 32 consecutive pixels, same b and h
    const int bb   = pix0 >> 12;             // / (64*64)
    const int hh   = (pix0 >> 6) & 63;
    const int w0   = pix0 & 63;

    // ---- per-block clipped float coords for all (pixel, tap) ----
    for (int t = tid; t < TM * KN; t += 256) {
        int p = t & (TM - 1);
        int n = t >> 5;
        const float* op = off + (size_t)(pix0 + p) * (2 * KN) + 2 * n;
        float y = (float)(hh - 1) + c_init_i[n] + op[0];
        float x = (float)(w0 + p - 1) + c_init_j[n] + op[1];
        y = fminf(fmaxf(y, 0.f), 63.f);
        x = fminf(fmaxf(x, 0.f), 63.f);
        cY[p][n] = y;
        cX[p][n] = x;
    }
    __syncthreads();

    const int wave = tid >> 6;
    const int lane = tid & 63;
    const int quad = lane >> 4;
    const int col  = lane & 15;
    const int mt   = wave & 1;          // M-tile (0..1)
    const int nt0  = (wave >> 1) * 4;   // first of 4 N-tiles

    f32x4 acc[4];
#pragma unroll
    for (int t = 0; t < 4; ++t) acc[t] = (f32x4){0.f, 0.f, 0.f, 0.f};

    const float* bbase = xin + ((size_t)bb << 19);  // b * 64*64*128

    for (int n = 0; n < KN; ++n) {
        // ---- stage Bt: contiguous copy of Wt[n] (N x K, bf16) ----
        const unsigned short* Wn = Wt + n * (CC * FF);
        for (int i = tid; i < (FF * CC) / 8; i += 256) {  // 2048 x 16B
            int f = i >> 4;
            int o = (i & 15) * 8;
            *(us8*)&Bt[f][o] = *(const us8*)(Wn + f * CC + o);
        }
        // ---- stage As: bilinear gather, 32 pixels x 128 ch ----
        for (int i = tid; i < TM * (CC / 4); i += 256) {
            int p  = i >> 5;
            int cg = (i & 31) * 4;
            float y = cY[p][n], x = cX[p][n];
            float fy0 = floorf(y), fx0 = floorf(x);
            int y0 = (int)fy0, x0 = (int)fx0;
            int y1 = (int)ceilf(y), x1 = (int)ceilf(x);
            float fy = y - fy0, fx = x - fx0;
            const float4 vlt = *(const float4*)(bbase + ((((y0 << 6) + x0) << 7) + cg));
            const float4 vrt = *(const float4*)(bbase + ((((y1 << 6) + x0) << 7) + cg));
            const float4 vlb = *(const float4*)(bbase + ((((y0 << 6) + x1) << 7) + cg));
            const float4 vrb = *(const float4*)(bbase + ((((y1 << 6) + x1) << 7) + cg));
            float r0, r1, r2, r3;
            { float vt = vlt.x + (vrt.x - vlt.x) * fy; float vb = vlb.x + (vrb.x - vlb.x) * fy; r0 = vt + (vb - vt) * fx; }
            { float vt = vlt.y + (vrt.y - vlt.y) * fy; float vb = vlb.y + (vrb.y - vlb.y) * fy; r1 = vt + (vb - vt) * fx; }
            { float vt = vlt.z + (vrt.z - vlt.z) * fy; float vb = vlb.z + (vrb.z - vlb.z) * fy; r2 = vt + (vb - vt) * fx; }
            { float vt = vlt.w + (vrt.w - vlt.w) * fy; float vb = vlb.w + (vrb.w - vlb.w) * fy; r3 = vt + (vb - vt) * fx; }
            us4 pk;
            pk.x = f2bf(r0); pk.y = f2bf(r1); pk.z = f2bf(r2); pk.w = f2bf(r3);
            *(us4*)&As[p][cg] = pk;
        }
        __syncthreads();

        // ---- MFMA: 4 K-steps of 32 over this tap's K-chunk of 128 ----
        const unsigned short* arow = &As[mt * 16 + col][0];
#pragma unroll
        for (int ks = 0; ks < 4; ++ks) {
            bf16x8 a = __builtin_bit_cast(bf16x8, *(const us8*)(arow + ks * 32 + quad * 8));
#pragma unroll
            for (int t = 0; t < 4; ++t) {
                bf16x8 b = __builtin_bit_cast(bf16x8,
                    *(const us8*)(&Bt[(nt0 + t) * 16 + col][ks * 32 + quad * 8]));
                acc[t] = __builtin_amdgcn_mfma_f32_16x16x32_bf16(a, b, acc[t], 0, 0, 0);
            }
        }
        __syncthreads();  // protect As/Bt overwrite next tap
    }

    // ---- epilogue: C/D layout col=lane&15, row=quad*4+reg ----
#pragma unroll
    for (int t = 0; t < 4; ++t) {
        int f = (nt0 + t) * 16 + col;
        float bv = bias[f];
#pragma unroll
        for (int r = 0; r < 4; ++r) {
            int pr = pix0 + mt * 16 + quad * 4 + r;
            out[(size_t)pr * FF + f] = acc[t][r] + bv;
        }
    }
}

extern "C" void kernel_launch(void* const* d_in, const int* in_sizes, int n_in,
                              void* d_out, int out_size, void* d_ws, size_t ws_size,
                              hipStream_t stream) {
    const float* x    = (const float*)d_in[0];
    const float* off  = (const float*)d_in[1];
    const float* Wk   = (const float*)d_in[2];
    const float* bias = (const float*)d_in[3];
    float* out = (float*)d_out;
    unsigned short* Wt = (unsigned short*)d_ws;  // 9*128*128 bf16 = 294912 B

    wt_kernel<<<(KN * CC * FF + 255) / 256, 256, 0, stream>>>(Wk, Wt);
    deform_kernel<<<(8 * HH * WW) / TM, 256, 0, stream>>>(x, off, Wt, bias, out);
}

// Round 4
// 130.661 us; speedup vs baseline: 1.0544x; 1.0544x over previous
//
#include <hip/hip_runtime.h>
#include <stdint.h>

#define KN 9
#define HH 64
#define WW 64
#define CC 128
#define FF 128
#define TM 64      // pixels per block (one full image row)
#define NT 512     // threads per block (8 waves)
#define LDK 136    // padded LDS K-stride (bf16 elements)

typedef __bf16 bf16x8 __attribute__((ext_vector_type(8)));
typedef float f32x4 __attribute__((ext_vector_type(4)));
typedef unsigned short us8 __attribute__((ext_vector_type(8)));
typedef unsigned short us4 __attribute__((ext_vector_type(4)));

// Reference tap layout: stack(meshgrid(ij)) shape (2,3,3); reshape(-1,2)
// flattens C-order (I-grid row-major, then J-grid row-major) and pairs
// CONSECUTIVE elements across the boundary:
//   seq  = [0,0,0,1,1,1,2,2,2, 0,1,2,0,1,2,0,1,2]
//   taps = (0,0)(0,1)(1,1)(2,2)(2,0)(1,2)(0,1)(2,0)(1,2)
// NOT a permutation of the 3x3 grid — faithful to the TF quirk. (verified R3)
__constant__ float c_init_i[KN] = {0.f,0.f,1.f,2.f,2.f,1.f,0.f,2.f,1.f};
__constant__ float c_init_j[KN] = {0.f,1.f,1.f,2.f,0.f,2.f,1.f,0.f,2.f};

static __device__ inline unsigned short f2bf(float f) {
    union { float f; unsigned u; } v; v.f = f;
    unsigned r = v.u + 0x7fffu + ((v.u >> 16) & 1u);  // RNE
    return (unsigned short)(r >> 16);
}

// Transpose + quantize W: (KN, C, F) fp32 -> Wt (KN, F, C) bf16.
// Coalesced READS (idx walks input layout); scattered 2B writes are
// fire-and-forget and don't stall the wave.
__global__ void wt_kernel(const float* __restrict__ Wk, unsigned short* __restrict__ Wt) {
    int idx = blockIdx.x * 256 + threadIdx.x;
    if (idx >= KN * CC * FF) return;
    int n = idx >> 14;            // /(128*128)
    int rem = idx & 16383;
    int c = rem >> 7;
    int f = rem & 127;
    Wt[(n << 14) + (f << 7) + c] = f2bf(Wk[idx]);
}

__launch_bounds__(NT, 4)
__global__ void deform_kernel(const float* __restrict__ xin,
                              const float* __restrict__ off,
                              const unsigned short* __restrict__ Wt,
                              const float* __restrict__ bias,
                              float* __restrict__ out) {
    __shared__ unsigned short As[TM][LDK];   // deform tile, bf16, M x Kchunk
    __shared__ unsigned short Bt[FF][LDK];   // W tap, bf16, N x Kchunk (B^T layout)
    __shared__ float cY[TM][KN];
    __shared__ float cX[TM][KN];
    // total: 17408 + 34816 + 2304 + 2304 = 56832 B -> 2 blocks/CU (LDS-capped)

    const int tid  = threadIdx.x;
    const int pix0 = blockIdx.x * TM;        // 64 consecutive pixels = row (b,h)
    const int bb   = pix0 >> 12;             // / (64*64)
    const int hh   = (pix0 >> 6) & 63;
    // w0 == 0 always (TM=64 aligns blocks to full rows)

    // ---- per-block clipped float coords for all (pixel, tap) ----
    for (int t = tid; t < TM * KN; t += NT) {
        int p = t & (TM - 1);
        int n = t >> 6;
        const float* op = off + (size_t)(pix0 + p) * (2 * KN) + 2 * n;
        float y = (float)(hh - 1) + c_init_i[n] + op[0];
        float x = (float)(p - 1) + c_init_j[n] + op[1];
        y = fminf(fmaxf(y, 0.f), 63.f);
        x = fminf(fmaxf(x, 0.f), 63.f);
        cY[p][n] = y;
        cX[p][n] = x;
    }
    __syncthreads();

    const int wave = tid >> 6;
    const int lane = tid & 63;
    const int quad = lane >> 4;
    const int col  = lane & 15;
    const int mt   = wave & 3;          // M-tile (0..3)
    const int nt0  = (wave >> 2) * 4;   // first of 4 N-tiles (0 or 4)

    f32x4 acc[4];
#pragma unroll
    for (int t = 0; t < 4; ++t) acc[t] = (f32x4){0.f, 0.f, 0.f, 0.f};

    const float* bbase = xin + ((size_t)bb << 19);  // b * 64*64*128

    for (int n = 0; n < KN; ++n) {
        // ---- stage Bt: contiguous copy of Wt[n] (N x K, bf16) ----
        const unsigned short* Wn = Wt + n * (CC * FF);
        for (int i = tid; i < (FF * CC) / 8; i += NT) {  // 2048 x 16B
            int f = i >> 4;
            int o = (i & 15) * 8;
            *(us8*)&Bt[f][o] = *(const us8*)(Wn + f * CC + o);
        }
        // ---- stage As: bilinear gather, 64 pixels x 128 ch ----
        for (int i = tid; i < TM * (CC / 4); i += NT) {
            int p  = i >> 5;
            int cg = (i & 31) * 4;
            float y = cY[p][n], x = cX[p][n];
            float fy0 = floorf(y), fx0 = floorf(x);
            int y0 = (int)fy0, x0 = (int)fx0;
            int y1 = (int)ceilf(y), x1 = (int)ceilf(x);
            float fy = y - fy0, fx = x - fx0;
            const float4 vlt = *(const float4*)(bbase + ((((y0 << 6) + x0) << 7) + cg));
            const float4 vrt = *(const float4*)(bbase + ((((y1 << 6) + x0) << 7) + cg));
            const float4 vlb = *(const float4*)(bbase + ((((y0 << 6) + x1) << 7) + cg));
            const float4 vrb = *(const float4*)(bbase + ((((y1 << 6) + x1) << 7) + cg));
            float r0, r1, r2, r3;
            { float vt = vlt.x + (vrt.x - vlt.x) * fy; float vb = vlb.x + (vrb.x - vlb.x) * fy; r0 = vt + (vb - vt) * fx; }
            { float vt = vlt.y + (vrt.y - vlt.y) * fy; float vb = vlb.y + (vrb.y - vlb.y) * fy; r1 = vt + (vb - vt) * fx; }
            { float vt = vlt.z + (vrt.z - vlt.z) * fy; float vb = vlb.z + (vrb.z - vlb.z) * fy; r2 = vt + (vb - vt) * fx; }
            { float vt = vlt.w + (vrt.w - vlt.w) * fy; float vb = vlb.w + (vrb.w - vlb.w) * fy; r3 = vt + (vb - vt) * fx; }
            us4 pk;
            pk.x = f2bf(r0); pk.y = f2bf(r1); pk.z = f2bf(r2); pk.w = f2bf(r3);
            *(us4*)&As[p][cg] = pk;
        }
        __syncthreads();

        // ---- MFMA: 4 K-steps of 32 over this tap's K-chunk of 128 ----
        const unsigned short* arow = &As[mt * 16 + col][0];
#pragma unroll
        for (int ks = 0; ks < 4; ++ks) {
            bf16x8 a = __builtin_bit_cast(bf16x8, *(const us8*)(arow + ks * 32 + quad * 8));
#pragma unroll
            for (int t = 0; t < 4; ++t) {
                bf16x8 b = __builtin_bit_cast(bf16x8,
                    *(const us8*)(&Bt[(nt0 + t) * 16 + col][ks * 32 + quad * 8]));
                acc[t] = __builtin_amdgcn_mfma_f32_16x16x32_bf16(a, b, acc[t], 0, 0, 0);
            }
        }
        __syncthreads();  // protect As/Bt overwrite next tap
    }

    // ---- epilogue: C/D layout col=lane&15, row=quad*4+reg (HW-verified) ----
#pragma unroll
    for (int t = 0; t < 4; ++t) {
        int f = (nt0 + t) * 16 + col;
        float bv = bias[f];
#pragma unroll
        for (int r = 0; r < 4; ++r) {
            int pr = pix0 + mt * 16 + quad * 4 + r;
            out[(size_t)pr * FF + f] = acc[t][r] + bv;
        }
    }
}

extern "C" void kernel_launch(void* const* d_in, const int* in_sizes, int n_in,
                              void* d_out, int out_size, void* d_ws, size_t ws_size,
                              hipStream_t stream) {
    const float* x    = (const float*)d_in[0];
    const float* off  = (const float*)d_in[1];
    const float* Wk   = (const float*)d_in[2];
    const float* bias = (const float*)d_in[3];
    float* out = (float*)d_out;
    unsigned short* Wt = (unsigned short*)d_ws;  // 9*128*128 bf16 = 294912 B

    wt_kernel<<<(KN * CC * FF + 255) / 256, 256, 0, stream>>>(Wk, Wt);
    deform_kernel<<<(8 * HH * WW) / TM, NT, 0, stream>>>(x, off, Wt, bias, out);
}

// Round 5
// 111.820 us; speedup vs baseline: 1.2320x; 1.1685x over previous
//
#include <hip/hip_runtime.h>
#include <stdint.h>

#define KN 9
#define HH 64
#define WW 64
#define CC 128
#define FF 128
#define TM 64      // pixels per block (one full image row)
#define NT 512     // threads per block (8 waves)
#define LDK 136    // padded LDS K-stride (bf16 elements)

typedef __bf16 bf16x8 __attribute__((ext_vector_type(8)));
typedef float f32x4 __attribute__((ext_vector_type(4)));
typedef unsigned short us8 __attribute__((ext_vector_type(8)));
typedef unsigned short us4 __attribute__((ext_vector_type(4)));

// Reference tap layout: stack(meshgrid(ij)) shape (2,3,3); reshape(-1,2)
// flattens C-order (I-grid row-major, then J-grid row-major) and pairs
// CONSECUTIVE elements across the boundary:
//   seq  = [0,0,0,1,1,1,2,2,2, 0,1,2,0,1,2,0,1,2]
//   taps = (0,0)(0,1)(1,1)(2,2)(2,0)(1,2)(0,1)(2,0)(1,2)
// NOT a permutation of the 3x3 grid — faithful to the TF quirk. (verified R3)
__constant__ float c_init_i[KN] = {0.f,0.f,1.f,2.f,2.f,1.f,0.f,2.f,1.f};
__constant__ float c_init_j[KN] = {0.f,1.f,1.f,2.f,0.f,2.f,1.f,0.f,2.f};

static __device__ inline unsigned short f2bf(float f) {
    union { float f; unsigned u; } v; v.f = f;
    unsigned r = v.u + 0x7fffu + ((v.u >> 16) & 1u);  // RNE
    return (unsigned short)(r >> 16);
}

// Transpose + quantize W: (KN, C, F) fp32 -> Wt (KN, F, C) bf16.
// Coalesced READS; scattered 2B writes are fire-and-forget.
__global__ void wt_kernel(const float* __restrict__ Wk, unsigned short* __restrict__ Wt) {
    int idx = blockIdx.x * 256 + threadIdx.x;
    if (idx >= KN * CC * FF) return;
    int n = idx >> 14;            // /(128*128)
    int rem = idx & 16383;
    int c = rem >> 7;
    int f = rem & 127;
    Wt[(n << 14) + (f << 7) + c] = f2bf(Wk[idx]);
}

__launch_bounds__(NT, 4)
__global__ void deform_kernel(const float* __restrict__ xin,
                              const float* __restrict__ off,
                              const unsigned short* __restrict__ Wt,
                              const float* __restrict__ bias,
                              float* __restrict__ out) {
    __shared__ unsigned short As[TM][LDK];   // deform tile, bf16, M x Kchunk
    __shared__ unsigned short Bt[FF][LDK];   // W tap, bf16, N x Kchunk (B^T layout)
    __shared__ float cY[TM][KN];
    __shared__ float cX[TM][KN];
    // total: 56832 B -> 2 blocks/CU (LDS-capped)

    const int tid = threadIdx.x;
    // XCD-aware swizzle: physical blocks go round-robin to XCDs (p % 8).
    // Put image b on XCD b so each XCD's 4 MiB L2 holds ONE 2 MB image
    // across all 9 tap passes. (R4: without this, FETCH_SIZE = 196 MB for a
    // 17 MB input — every XCD thrashed on the full 8-image working set.)
    const int bb   = blockIdx.x & 7;         // image  -> XCD
    const int hh   = blockIdx.x >> 3;        // row within image
    const int pix0 = (bb << 12) + (hh << 6); // b*4096 + h*64

    // ---- per-block clipped float coords for all (pixel, tap) ----
    for (int t = tid; t < TM * KN; t += NT) {
        int p = t & (TM - 1);
        int n = t >> 6;
        const float* op = off + (size_t)(pix0 + p) * (2 * KN) + 2 * n;
        float y = (float)(hh - 1) + c_init_i[n] + op[0];
        float x = (float)(p - 1) + c_init_j[n] + op[1];
        y = fminf(fmaxf(y, 0.f), 63.f);
        x = fminf(fmaxf(x, 0.f), 63.f);
        cY[p][n] = y;
        cX[p][n] = x;
    }
    __syncthreads();

    const int wave = tid >> 6;
    const int lane = tid & 63;
    const int quad = lane >> 4;
    const int col  = lane & 15;
    const int mt   = wave & 3;          // M-tile (0..3)
    const int nt0  = (wave >> 2) * 4;   // first of 4 N-tiles (0 or 4)

    f32x4 acc[4];
#pragma unroll
    for (int t = 0; t < 4; ++t) acc[t] = (f32x4){0.f, 0.f, 0.f, 0.f};

    const float* bbase = xin + ((size_t)bb << 19);  // b * 64*64*128

    for (int n = 0; n < KN; ++n) {
        // ---- stage Bt: contiguous copy of Wt[n] (N x K, bf16) ----
        const unsigned short* Wn = Wt + n * (CC * FF);
        for (int i = tid; i < (FF * CC) / 8; i += NT) {  // 2048 x 16B
            int f = i >> 4;
            int o = (i & 15) * 8;
            *(us8*)&Bt[f][o] = *(const us8*)(Wn + f * CC + o);
        }
        // ---- stage As: bilinear gather, 64 pixels x 128 ch ----
        for (int i = tid; i < TM * (CC / 4); i += NT) {
            int p  = i >> 5;
            int cg = (i & 31) * 4;
            float y = cY[p][n], x = cX[p][n];
            float fy0 = floorf(y), fx0 = floorf(x);
            int y0 = (int)fy0, x0 = (int)fx0;
            int y1 = (int)ceilf(y), x1 = (int)ceilf(x);
            float fy = y - fy0, fx = x - fx0;
            const float4 vlt = *(const float4*)(bbase + ((((y0 << 6) + x0) << 7) + cg));
            const float4 vrt = *(const float4*)(bbase + ((((y1 << 6) + x0) << 7) + cg));
            const float4 vlb = *(const float4*)(bbase + ((((y0 << 6) + x1) << 7) + cg));
            const float4 vrb = *(const float4*)(bbase + ((((y1 << 6) + x1) << 7) + cg));
            float r0, r1, r2, r3;
            { float vt = vlt.x + (vrt.x - vlt.x) * fy; float vb = vlb.x + (vrb.x - vlb.x) * fy; r0 = vt + (vb - vt) * fx; }
            { float vt = vlt.y + (vrt.y - vlt.y) * fy; float vb = vlb.y + (vrb.y - vlb.y) * fy; r1 = vt + (vb - vt) * fx; }
            { float vt = vlt.z + (vrt.z - vlt.z) * fy; float vb = vlb.z + (vrb.z - vlb.z) * fy; r2 = vt + (vb - vt) * fx; }
            { float vt = vlt.w + (vrt.w - vlt.w) * fy; float vb = vlb.w + (vrb.w - vlb.w) * fy; r3 = vt + (vb - vt) * fx; }
            us4 pk;
            pk.x = f2bf(r0); pk.y = f2bf(r1); pk.z = f2bf(r2); pk.w = f2bf(r3);
            *(us4*)&As[p][cg] = pk;
        }
        __syncthreads();

        // ---- MFMA: 4 K-steps of 32 over this tap's K-chunk of 128 ----
        const unsigned short* arow = &As[mt * 16 + col][0];
#pragma unroll
        for (int ks = 0; ks < 4; ++ks) {
            bf16x8 a = __builtin_bit_cast(bf16x8, *(const us8*)(arow + ks * 32 + quad * 8));
#pragma unroll
            for (int t = 0; t < 4; ++t) {
                bf16x8 b = __builtin_bit_cast(bf16x8,
                    *(const us8*)(&Bt[(nt0 + t) * 16 + col][ks * 32 + quad * 8]));
                acc[t] = __builtin_amdgcn_mfma_f32_16x16x32_bf16(a, b, acc[t], 0, 0, 0);
            }
        }
        __syncthreads();  // protect As/Bt overwrite next tap
    }

    // ---- epilogue: C/D layout col=lane&15, row=quad*4+reg (HW-verified) ----
#pragma unroll
    for (int t = 0; t < 4; ++t) {
        int f = (nt0 + t) * 16 + col;
        float bv = bias[f];
#pragma unroll
        for (int r = 0; r < 4; ++r) {
            int pr = pix0 + mt * 16 + quad * 4 + r;
            out[(size_t)pr * FF + f] = acc[t][r] + bv;
        }
    }
}

extern "C" void kernel_launch(void* const* d_in, const int* in_sizes, int n_in,
                              void* d_out, int out_size, void* d_ws, size_t ws_size,
                              hipStream_t stream) {
    const float* x    = (const float*)d_in[0];
    const float* off  = (const float*)d_in[1];
    const float* Wk   = (const float*)d_in[2];
    const float* bias = (const float*)d_in[3];
    float* out = (float*)d_out;
    unsigned short* Wt = (unsigned short*)d_ws;  // 9*128*128 bf16 = 294912 B

    wt_kernel<<<(KN * CC * FF + 255) / 256, 256, 0, stream>>>(Wk, Wt);
    deform_kernel<<<(8 * HH * WW) / TM, NT, 0, stream>>>(x, off, Wt, bias, out);
}

// Round 6
// 104.942 us; speedup vs baseline: 1.3128x; 1.0655x over previous
//
#include <hip/hip_runtime.h>
#include <stdint.h>

#define KN 9
#define HH 64
#define WW 64
#define CC 128
#define FF 128
#define TM 64      // pixels per block (one full image row)
#define NT 512     // threads per block (8 waves)
#define LDK 136    // padded LDS K-stride (bf16 elements)

typedef __bf16 bf16x8 __attribute__((ext_vector_type(8)));
typedef float f32x4 __attribute__((ext_vector_type(4)));
typedef unsigned short us8 __attribute__((ext_vector_type(8)));
typedef unsigned short us4 __attribute__((ext_vector_type(4)));

// Reference tap layout (verified R3): stack(meshgrid(ij)).reshape(-1,2) pairs
// the C-order flatten of (2,3,3) across the I/J boundary:
//   taps = (0,0)(0,1)(1,1)(2,2)(2,0)(1,2)(0,1)(2,0)(1,2)
__constant__ float c_init_i[KN] = {0.f,0.f,1.f,2.f,2.f,1.f,0.f,2.f,1.f};
__constant__ float c_init_j[KN] = {0.f,1.f,1.f,2.f,0.f,2.f,1.f,0.f,2.f};

static __device__ inline unsigned short f2bf(float f) {
    union { float f; unsigned u; } v; v.f = f;
    unsigned r = v.u + 0x7fffu + ((v.u >> 16) & 1u);  // RNE
    return (unsigned short)(r >> 16);
}

// Transpose + quantize W: (KN, C, F) fp32 -> Wt (KN, F, C) bf16.
// LDS 32x32 tile transpose: coalesced reads AND coalesced writes
// (R5: scattered 2B writes cost ~300k write transactions).
__global__ void wt_kernel(const float* __restrict__ Wk, unsigned short* __restrict__ Wt) {
    __shared__ unsigned short t[32][33];
    const int tid = threadIdx.x;
    const int n  = blockIdx.x >> 4;
    const int tf = blockIdx.x & 3;        // f-tile
    const int tc = (blockIdx.x >> 2) & 3; // c-tile
    const int g  = tid >> 5;              // 0..7
    const int l  = tid & 31;
#pragma unroll
    for (int r = 0; r < 4; ++r) {
        int cl = g * 4 + r;
        t[cl][l] = f2bf(Wk[(n << 14) + ((tc * 32 + cl) << 7) + (tf * 32 + l)]);
    }
    __syncthreads();
#pragma unroll
    for (int r = 0; r < 4; ++r) {
        int fl = g * 4 + r;
        Wt[(n << 14) + ((tf * 32 + fl) << 7) + (tc * 32 + l)] = t[l][fl];
    }
}

__launch_bounds__(NT, 4)   // cap at 128 VGPR: 2 blocks/CU needs 4 waves/SIMD
__global__ void deform_kernel(const float* __restrict__ xin,
                              const float* __restrict__ off,
                              const unsigned short* __restrict__ Wt,
                              const float* __restrict__ bias,
                              float* __restrict__ out) {
    __shared__ unsigned short As[TM][LDK];   // deform tile, bf16, M x K
    __shared__ unsigned short Bt[FF][LDK];   // W tap, bf16, N x K (B^T layout)
    __shared__ float cY[TM][KN];
    __shared__ float cX[TM][KN];
    // 17408 + 34816 + 2304 + 2304 = 56832 B -> 2 blocks/CU

    const int tid = threadIdx.x;
    // XCD swizzle (verified R5: FETCH 196->10.5 MB): image b -> XCD b.
    const int bb   = blockIdx.x & 7;
    const int hh   = blockIdx.x >> 3;
    const int pix0 = (bb << 12) + (hh << 6);

    for (int t = tid; t < TM * KN; t += NT) {
        int p = t & (TM - 1);
        int n = t >> 6;
        const float* op = off + (size_t)(pix0 + p) * (2 * KN) + 2 * n;
        float y = (float)(hh - 1) + c_init_i[n] + op[0];
        float x = (float)(p - 1) + c_init_j[n] + op[1];
        cY[p][n] = fminf(fmaxf(y, 0.f), 63.f);
        cX[p][n] = fminf(fmaxf(x, 0.f), 63.f);
    }
    __syncthreads();

    const int wave = tid >> 6;
    const int lane = tid & 63;
    const int quad = lane >> 4;
    const int col  = lane & 15;
    const int mtile = (wave & 1) * 32;   // 2 M-supertiles of 32 pixels
    const int ntile = (wave >> 1) * 32;  // 4 N-supertiles of 32 filters

    f32x4 acc[2][2];
#pragma unroll
    for (int a = 0; a < 2; ++a)
#pragma unroll
        for (int b = 0; b < 2; ++b) acc[a][b] = (f32x4){0.f, 0.f, 0.f, 0.f};

    const float* bbase = xin + ((size_t)bb << 19);

    // issue the 4 corner loads for gather item k of tap n (no wait)
    auto issue_gather = [&](int n, int k, float4* pf) {
        int i  = tid + k * NT;
        int p  = i >> 5;
        int cg = (i & 31) * 4;
        float y = cY[p][n], x = cX[p][n];
        int y0 = (int)floorf(y), x0 = (int)floorf(x);
        int y1 = (int)ceilf(y),  x1 = (int)ceilf(x);
        pf[0] = *(const float4*)(bbase + ((((y0 << 6) + x0) << 7) + cg));
        pf[1] = *(const float4*)(bbase + ((((y1 << 6) + x0) << 7) + cg));
        pf[2] = *(const float4*)(bbase + ((((y0 << 6) + x1) << 7) + cg));
        pf[3] = *(const float4*)(bbase + ((((y1 << 6) + x1) << 7) + cg));
    };
    // interp prefetched corners and write As
    auto consume = [&](int n, int k, const float4* pf) {
        int i  = tid + k * NT;
        int p  = i >> 5;
        int cg = (i & 31) * 4;
        float y = cY[p][n], x = cX[p][n];
        float fy = y - floorf(y), fx = x - floorf(x);
        float r0, r1, r2, r3;
        { float vt = pf[0].x + (pf[1].x - pf[0].x) * fy; float vb = pf[2].x + (pf[3].x - pf[2].x) * fy; r0 = vt + (vb - vt) * fx; }
        { float vt = pf[0].y + (pf[1].y - pf[0].y) * fy; float vb = pf[2].y + (pf[3].y - pf[2].y) * fy; r1 = vt + (vb - vt) * fx; }
        { float vt = pf[0].z + (pf[1].z - pf[0].z) * fy; float vb = pf[2].z + (pf[3].z - pf[2].z) * fy; r2 = vt + (vb - vt) * fx; }
        { float vt = pf[0].w + (pf[1].w - pf[0].w) * fy; float vb = pf[2].w + (pf[3].w - pf[2].w) * fy; r3 = vt + (vb - vt) * fx; }
        us4 pk;
        pk.x = f2bf(r0); pk.y = f2bf(r1); pk.z = f2bf(r2); pk.w = f2bf(r3);
        *(us4*)&As[p][cg] = pk;
    };

    // ---- prologue: prefetch tap 0 (items 0,1 + Bt rows) ----
    float4 pf0[4], pf1[4];
    us8 bpf[4];
    issue_gather(0, 0, pf0);
    issue_gather(0, 1, pf1);
#pragma unroll
    for (int k = 0; k < 4; ++k) {
        int i2 = tid + k * NT;
        bpf[k] = *(const us8*)(Wt + (i2 >> 4) * CC + (i2 & 15) * 8);
    }

    for (int n = 0; n < KN; ++n) {
        // issue this tap's remaining gather items (overlap with consume below)
        float4 pf2[4], pf3[4];
        issue_gather(n, 2, pf2);
        issue_gather(n, 3, pf3);
        // write Bt from prefetched regs
#pragma unroll
        for (int k = 0; k < 4; ++k) {
            int i2 = tid + k * NT;
            *(us8*)&Bt[i2 >> 4][(i2 & 15) * 8] = bpf[k];
        }
        // interp + write As
        consume(n, 0, pf0);
        consume(n, 1, pf1);
        consume(n, 2, pf2);
        consume(n, 3, pf3);
        __syncthreads();   // As/Bt ready

        // prefetch NEXT tap before the MFMA phase: loads fly under MFMA+LDS
        if (n + 1 < KN) {
            issue_gather(n + 1, 0, pf0);
            issue_gather(n + 1, 1, pf1);
            const unsigned short* Wn = Wt + (n + 1) * (CC * FF);
#pragma unroll
            for (int k = 0; k < 4; ++k) {
                int i2 = tid + k * NT;
                bpf[k] = *(const us8*)(Wn + (i2 >> 4) * CC + (i2 & 15) * 8);
            }
        }

        // ---- MFMA: 32x32 wave tile, 4 K-steps of 32 ----
#pragma unroll
        for (int ks = 0; ks < 4; ++ks) {
            bf16x8 a0 = __builtin_bit_cast(bf16x8, *(const us8*)(&As[mtile + col][ks * 32 + quad * 8]));
            bf16x8 a1 = __builtin_bit_cast(bf16x8, *(const us8*)(&As[mtile + 16 + col][ks * 32 + quad * 8]));
            bf16x8 b0 = __builtin_bit_cast(bf16x8, *(const us8*)(&Bt[ntile + col][ks * 32 + quad * 8]));
            bf16x8 b1 = __builtin_bit_cast(bf16x8, *(const us8*)(&Bt[ntile + 16 + col][ks * 32 + quad * 8]));
            acc[0][0] = __builtin_amdgcn_mfma_f32_16x16x32_bf16(a0, b0, acc[0][0], 0, 0, 0);
            acc[0][1] = __builtin_amdgcn_mfma_f32_16x16x32_bf16(a0, b1, acc[0][1], 0, 0, 0);
            acc[1][0] = __builtin_amdgcn_mfma_f32_16x16x32_bf16(a1, b0, acc[1][0], 0, 0, 0);
            acc[1][1] = __builtin_amdgcn_mfma_f32_16x16x32_bf16(a1, b1, acc[1][1], 0, 0, 0);
        }
        __syncthreads();   // protect As/Bt overwrite next tap
    }

    // ---- epilogue: C/D layout col=lane&15, row=quad*4+reg (HW-verified) ----
#pragma unroll
    for (int b = 0; b < 2; ++b) {
        int f = ntile + b * 16 + col;
        float bv = bias[f];
#pragma unroll
        for (int a = 0; a < 2; ++a) {
#pragma unroll
            for (int r = 0; r < 4; ++r) {
                int pr = pix0 + mtile + a * 16 + quad * 4 + r;
                out[(size_t)pr * FF + f] = acc[a][b][r] + bv;
            }
        }
    }
}

extern "C" void kernel_launch(void* const* d_in, const int* in_sizes, int n_in,
                              void* d_out, int out_size, void* d_ws, size_t ws_size,
                              hipStream_t stream) {
    const float* x    = (const float*)d_in[0];
    const float* off  = (const float*)d_in[1];
    const float* Wk   = (const float*)d_in[2];
    const float* bias = (const float*)d_in[3];
    float* out = (float*)d_out;
    unsigned short* Wt = (unsigned short*)d_ws;  // 9*128*128 bf16 = 294912 B

    wt_kernel<<<KN * 16, 256, 0, stream>>>(Wk, Wt);
    deform_kernel<<<(8 * HH * WW) / TM, NT, 0, stream>>>(x, off, Wt, bias, out);
}